// Round 7
// baseline (382.277 us; speedup 1.0000x reference)
//
#include <hip/hip_runtime.h>
#include <hip/hip_bf16.h>

// Problem constants: B=2, T=4096, C=768, H=12, D=64
#define T_SEQ 4096
#define C_DIM 768
#define H_NUM 12
#define D_HEAD 64
#define N3    2304   // 3*C
#define BHN   24     // B*H

typedef __bf16 bf16x8 __attribute__((ext_vector_type(8)));
typedef float  f32x4  __attribute__((ext_vector_type(4)));

// fp32 -> bf16 (round-to-nearest-even), raw bits
__device__ inline unsigned short f2b(float f) {
    unsigned int x = __float_as_uint(f);
    unsigned int r = (x + 0x7FFFu + ((x >> 16) & 1u)) >> 16;
    return (unsigned short)r;
}

// pack two f32 -> two bf16 (TRUNCATED) in one v_perm_b32: low half = lo
__device__ inline unsigned int pack_trunc(float lo, float hi) {
    return __builtin_amdgcn_perm(__float_as_uint(hi), __float_as_uint(lo), 0x07060302u);
}

// 16B-per-lane async global->LDS (dest = wave-uniform base + lane*16)
__device__ inline void load_lds16(const unsigned short* g, unsigned short* l) {
    __builtin_amdgcn_global_load_lds(
        (const __attribute__((address_space(1))) unsigned int*)(g),
        (__attribute__((address_space(3))) unsigned int*)(l),
        16, 0, 0);
}

// ---------------------------------------------------------------------------
// prep: fused [convert x -> bf16] + [transpose qkv_w] + [transpose out_w]
// ---------------------------------------------------------------------------
__device__ inline void transpose_tile(const float* __restrict__ in,
                                      unsigned short* __restrict__ out,
                                      unsigned short* Ts, int k0, int n0,
                                      int R, int Cc, int tid)
{
    #pragma unroll
    for (int it = 0; it < 4; ++it) {
        int idx = tid + it * 256;
        int r = idx >> 4, c4 = idx & 15;
        float4 v = *reinterpret_cast<const float4*>(&in[(size_t)(k0 + r) * Cc + n0 + c4 * 4]);
        Ts[(c4 * 4 + 0) * 72 + r] = f2b(v.x);
        Ts[(c4 * 4 + 1) * 72 + r] = f2b(v.y);
        Ts[(c4 * 4 + 2) * 72 + r] = f2b(v.z);
        Ts[(c4 * 4 + 3) * 72 + r] = f2b(v.w);
    }
    __syncthreads();
    #pragma unroll
    for (int it = 0; it < 2; ++it) {
        int idx = tid + it * 256;
        int row = idx >> 3, ch = idx & 7;
        *reinterpret_cast<uint4*>(&out[(size_t)(n0 + row) * R + k0 + ch * 8]) =
            *reinterpret_cast<const uint4*>(&Ts[row * 72 + ch * 8]);
    }
}

__global__ __launch_bounds__(256) void prep(
    const float* __restrict__ x, const float* __restrict__ qkv_w,
    const float* __restrict__ out_w,
    unsigned short* __restrict__ xb, unsigned short* __restrict__ wtq,
    unsigned short* __restrict__ wto)
{
    __shared__ unsigned short Ts[64 * 72];
    const int b = blockIdx.x, tid = threadIdx.x;
    if (b < 6144) {
        int idx = b * 256 + tid;
        float4 v = reinterpret_cast<const float4*>(x)[idx];
        ushort4 u;
        u.x = f2b(v.x); u.y = f2b(v.y); u.z = f2b(v.z); u.w = f2b(v.w);
        reinterpret_cast<ushort4*>(xb)[idx] = u;
    } else if (b < 6576) {
        int bb = b - 6144;
        transpose_tile(qkv_w, wtq, Ts, (bb % 12) * 64, (bb / 12) * 64, C_DIM, N3, tid);
    } else {
        int bb = b - 6576;
        transpose_tile(out_w, wto, Ts, (bb % 12) * 64, (bb / 12) * 64, C_DIM, C_DIM, tid);
    }
}

// ---------------------------------------------------------------------------
// QKV projection: xb[8192,768] x wtq[2304,768]([n][k]) + bias, all bf16 MFMA.
// 128x128 tile, BK=64. Q scaled by 0.125*log2e. V written via LDS transpose
// (coalesced 16B stores) as [B,H,D,T].
// ---------------------------------------------------------------------------
__global__ __launch_bounds__(256) void qkv_gemm(
    const unsigned short* __restrict__ xb, const unsigned short* __restrict__ wt,
    const float* __restrict__ bias,
    unsigned short* __restrict__ Q, unsigned short* __restrict__ K,
    unsigned short* __restrict__ Vt)
{
    __shared__ unsigned short SH[128 * 128];   // As | Bs ; reused as Ct in V epilogue
    unsigned short* As = SH;                   // [128][64] xor-swizzled chunks
    unsigned short* Bs = SH + 128 * 64;        // [128][64]
    const int tid  = threadIdx.x;
    const int m0   = blockIdx.x * 128;
    const int n0   = blockIdx.y * 128;
    const int lane = tid & 63;
    const int wv   = tid >> 6;
    const int wr   = wv >> 1, wc = wv & 1;
    const int quad = lane >> 4;
    const int lr   = lane & 15;
    const int srow = lane >> 3;
    const int dch  = (lane & 7) ^ srow;

    f32x4 acc[4][4] = {};

    for (int kk = 0; kk < C_DIM; kk += 64) {
        __syncthreads();
        #pragma unroll
        for (int i = 0; i < 4; ++i) {
            int inst = wv * 4 + i;
            int r = inst * 8 + srow;
            load_lds16(xb + (size_t)(m0 + r) * C_DIM + kk + dch * 8, As + inst * 512);
            load_lds16(wt + (size_t)(n0 + r) * C_DIM + kk + dch * 8, Bs + inst * 512);
        }
        __syncthreads();
        #pragma unroll
        for (int k2 = 0; k2 < 2; ++k2) {
            bf16x8 af[4], bf[4];
            #pragma unroll
            for (int mt = 0; mt < 4; ++mt)
                af[mt] = *reinterpret_cast<const bf16x8*>(
                    &As[(wr * 64 + mt * 16 + lr) * 64 + (((k2 * 4 + quad) ^ (lr & 7)) * 8)]);
            #pragma unroll
            for (int nt = 0; nt < 4; ++nt)
                bf[nt] = *reinterpret_cast<const bf16x8*>(
                    &Bs[(wc * 64 + nt * 16 + lr) * 64 + (((k2 * 4 + quad) ^ (lr & 7)) * 8)]);
            #pragma unroll
            for (int mt = 0; mt < 4; ++mt)
                #pragma unroll
                for (int nt = 0; nt < 4; ++nt)
                    acc[mt][nt] = __builtin_amdgcn_mfma_f32_16x16x32_bf16(af[mt], bf[nt], acc[mt][nt], 0, 0, 0);
        }
    }

    const int whichblk = n0 / C_DIM;   // 0=Q,1=K,2=V (uniform; 768 % 128 == 0)
    if (whichblk == 2) {
        // --- V epilogue: transpose through LDS, coalesced 16B stores ---
        __syncthreads();
        #pragma unroll
        for (int nt = 0; nt < 4; ++nt) {
            int dp = wc * 64 + nt * 16 + lr;          // n within tile = 0..127
            float bj = bias[n0 + dp];
            #pragma unroll
            for (int mt = 0; mt < 4; ++mt) {
                int t0 = wr * 64 + mt * 16 + quad * 4;  // 4 consecutive t
                ushort4 u;
                u.x = f2b(acc[mt][nt][0] + bj);
                u.y = f2b(acc[mt][nt][1] + bj);
                u.z = f2b(acc[mt][nt][2] + bj);
                u.w = f2b(acc[mt][nt][3] + bj);
                int cs = (t0 >> 2) ^ ((dp & 15) << 1);   // even-XOR: keeps 16B pairs
                *reinterpret_cast<ushort4*>(&SH[dp * 128 + cs * 4]) = u;
            }
        }
        __syncthreads();
        const int bb = m0 >> 12;
        const int t_base = m0 & 4095;
        const int h_base = (n0 - 2 * C_DIM) >> 6;
        #pragma unroll
        for (int i = 0; i < 8; ++i) {
            int idx = i * 256 + tid;
            int row = idx >> 4, cc = idx & 15;
            int pc = ((2 * cc) ^ ((row & 15) << 1)) * 4;
            uint4 val = *reinterpret_cast<const uint4*>(&SH[row * 128 + pc]);
            int head = h_base + (row >> 6);
            int d = row & 63;
            *reinterpret_cast<uint4*>(
                &Vt[((size_t)(bb * H_NUM + head) * D_HEAD + d) * T_SEQ + t_base + cc * 8]) = val;
        }
    } else {
        // --- Q/K epilogue: direct stores (16-lane 32B segments) ---
        const int head0 = ((n0 % C_DIM) + wc * 64) >> 6;
        #pragma unroll
        for (int nt = 0; nt < 4; ++nt) {
            int d = nt * 16 + lr;
            float bj = bias[n0 + wc * 64 + nt * 16 + lr];
            #pragma unroll
            for (int mt = 0; mt < 4; ++mt) {
                #pragma unroll
                for (int reg = 0; reg < 4; ++reg) {
                    int i = m0 + wr * 64 + mt * 16 + quad * 4 + reg;
                    int bb = i >> 12, t = i & 4095;
                    float val = acc[mt][nt][reg] + bj;
                    size_t base = (size_t)(bb * H_NUM + head0) * T_SEQ + t;
                    if (whichblk == 0)
                        Q[base * D_HEAD + d] = f2b(val * 0.18033688011f);  // 0.125*log2(e)
                    else
                        K[base * D_HEAD + d] = f2b(val);
                }
            }
        }
    }
}

// ---------------------------------------------------------------------------
// Flash attention (causal), R7: BARRIER-FREE. One block = 128 queries of one
// (b,h); 4 waves x (16 q x 2 halves). K/V A-fragments read directly from
// global (16 fully line-coalesced 64B lines per instr); no K/V LDS staging,
// no __syncthreads anywhere -> waves free-run, VMEM prefetch flows under
// PV-MFMAs. XCD-swizzled block mapping pins each (b,h)'s K/V (3.1 MB for 3
// bh) inside one XCD's 4 MB L2. LDS holds only per-wave P strips (18 KB ->
// LDS allows 8 blocks/CU; VGPR is the occupancy cap). Max-free softmax in
// log2 domain; l via ones-MFMA; P packed via v_perm truncation.
// ---------------------------------------------------------------------------
__global__ __launch_bounds__(256, 3) void flash_attn(
    const unsigned short* __restrict__ Q, const unsigned short* __restrict__ K,
    const unsigned short* __restrict__ Vt, unsigned short* __restrict__ Y)
{
    __shared__ unsigned short Ps[2][64 * 72];   // [half][q][key] per-wave strips
    const int tid  = threadIdx.x;
    const int lane = tid & 63;
    const int wv   = tid >> 6;
    const int quad = lane >> 4;
    const int lr   = lane & 15;

    // XCD-aware mapping: bid%8 = XCD (HW round-robin); each XCD owns 3 bh.
    const int bid = blockIdx.x;
    const int xcd = bid & 7;
    const int jj  = (bid >> 3) % 3;
    const int bh  = xcd * 3 + jj;
    const int qt  = 31 - (bid / 24);      // heavy q-tiles first
    const int q0  = qt * 128;
    const int diag0 = 2 * qt;             // kt index of half-0 diagonal
    const int last  = diag0 + 1;          // kt index of half-1 diagonal

    const unsigned short* Qb = Q  + (size_t)bh * T_SEQ * D_HEAD;
    const unsigned short* Kb = K  + (size_t)bh * T_SEQ * D_HEAD;
    const unsigned short* Vb = Vt + (size_t)bh * D_HEAD * T_SEQ;

    // Q B-frags (n = q = lr); Q pre-scaled by 0.125*log2e
    bf16x8 bQ[2][2];
    #pragma unroll
    for (int h = 0; h < 2; ++h)
        #pragma unroll
        for (int k2 = 0; k2 < 2; ++k2)
            bQ[h][k2] = *reinterpret_cast<const bf16x8*>(
                &Qb[(size_t)(q0 + h * 64 + wv * 16 + lr) * D_HEAD + k2 * 32 + quad * 8]);

    bf16x8 ones;
    #pragma unroll
    for (int i = 0; i < 8; ++i) ones[i] = (__bf16)1.0f;
    const f32x4 zf = {};

    f32x4 oacc[2][4] = {};       // [half][dt]: row=d, col=q(lr)
    f32x4 lacc[2] = {};          // [half]: every reg = full column sum (l)

    unsigned short* Pw0 = &Ps[0][(wv * 16) * 72];
    unsigned short* Pw1 = &Ps[1][(wv * 16) * 72];

    for (int kt = 0; kt <= last; ++kt) {
        const bool doh0 = (kt <= diag0);
        const unsigned short* Kt = Kb + (size_t)kt * 64 * D_HEAD;

        // K A-frags direct from global (16 x 64B lines per instr, coalesced)
        bf16x8 aK[4][2];
        #pragma unroll
        for (int mt = 0; mt < 4; ++mt)
            #pragma unroll
            for (int k2 = 0; k2 < 2; ++k2)
                aK[mt][k2] = *reinterpret_cast<const bf16x8*>(
                    &Kt[(mt * 16 + lr) * D_HEAD + k2 * 32 + quad * 8]);

        // S^T[key][q] for both halves (independent MFMA chains)
        f32x4 st0[4], st1[4];
        #pragma unroll
        for (int mt = 0; mt < 4; ++mt) {
            st1[mt] = __builtin_amdgcn_mfma_f32_16x16x32_bf16(aK[mt][0], bQ[1][0], zf, 0, 0, 0);
            st1[mt] = __builtin_amdgcn_mfma_f32_16x16x32_bf16(aK[mt][1], bQ[1][1], st1[mt], 0, 0, 0);
        }
        if (doh0) {
            #pragma unroll
            for (int mt = 0; mt < 4; ++mt) {
                st0[mt] = __builtin_amdgcn_mfma_f32_16x16x32_bf16(aK[mt][0], bQ[0][0], zf, 0, 0, 0);
                st0[mt] = __builtin_amdgcn_mfma_f32_16x16x32_bf16(aK[mt][1], bQ[0][1], st0[mt], 0, 0, 0);
            }
        }

        // causal masks (diagonal tiles only)
        if (kt == diag0) {
            int qg = q0 + wv * 16 + lr;
            #pragma unroll
            for (int mt = 0; mt < 4; ++mt)
                #pragma unroll
                for (int reg = 0; reg < 4; ++reg)
                    if (kt * 64 + mt * 16 + quad * 4 + reg > qg) st0[mt][reg] = -INFINITY;
        }
        if (kt == last) {
            int qg = q0 + 64 + wv * 16 + lr;
            #pragma unroll
            for (int mt = 0; mt < 4; ++mt)
                #pragma unroll
                for (int reg = 0; reg < 4; ++reg)
                    if (kt * 64 + mt * 16 + quad * 4 + reg > qg) st1[mt][reg] = -INFINITY;
        }

        // p = exp2(s); pack truncated; write to per-half strips
        #pragma unroll
        for (int mt = 0; mt < 4; ++mt) {
            #pragma unroll
            for (int reg = 0; reg < 4; ++reg)
                st1[mt][reg] = __builtin_amdgcn_exp2f(st1[mt][reg]);
            uint2 u;
            u.x = pack_trunc(st1[mt][0], st1[mt][1]);
            u.y = pack_trunc(st1[mt][2], st1[mt][3]);
            *reinterpret_cast<uint2*>(&Pw1[lr * 72 + mt * 16 + quad * 4]) = u;
        }
        if (doh0) {
            #pragma unroll
            for (int mt = 0; mt < 4; ++mt) {
                #pragma unroll
                for (int reg = 0; reg < 4; ++reg)
                    st0[mt][reg] = __builtin_amdgcn_exp2f(st0[mt][reg]);
                uint2 u;
                u.x = pack_trunc(st0[mt][0], st0[mt][1]);
                u.y = pack_trunc(st0[mt][2], st0[mt][3]);
                *reinterpret_cast<uint2*>(&Pw0[lr * 72 + mt * 16 + quad * 4]) = u;
            }
        }

        // V A-frags direct from global (aK dead; register reuse)
        bf16x8 aV[4][2];
        #pragma unroll
        for (int mt = 0; mt < 4; ++mt)
            #pragma unroll
            for (int k2 = 0; k2 < 2; ++k2)
                aV[mt][k2] = *reinterpret_cast<const bf16x8*>(
                    &Vb[(size_t)(mt * 16 + lr) * T_SEQ + kt * 64 + k2 * 32 + quad * 8]);

        // O^T += V^T P^T ; l += 1^T P (ones-MFMA column sums)
        if (doh0) {
            bf16x8 bP0 = *reinterpret_cast<const bf16x8*>(&Pw0[lr * 72 + quad * 8]);
            bf16x8 bP1 = *reinterpret_cast<const bf16x8*>(&Pw0[lr * 72 + 32 + quad * 8]);
            #pragma unroll
            for (int dt = 0; dt < 4; ++dt) {
                oacc[0][dt] = __builtin_amdgcn_mfma_f32_16x16x32_bf16(aV[dt][0], bP0, oacc[0][dt], 0, 0, 0);
                oacc[0][dt] = __builtin_amdgcn_mfma_f32_16x16x32_bf16(aV[dt][1], bP1, oacc[0][dt], 0, 0, 0);
            }
            lacc[0] = __builtin_amdgcn_mfma_f32_16x16x32_bf16(ones, bP0, lacc[0], 0, 0, 0);
            lacc[0] = __builtin_amdgcn_mfma_f32_16x16x32_bf16(ones, bP1, lacc[0], 0, 0, 0);
        }
        {
            bf16x8 bP0 = *reinterpret_cast<const bf16x8*>(&Pw1[lr * 72 + quad * 8]);
            bf16x8 bP1 = *reinterpret_cast<const bf16x8*>(&Pw1[lr * 72 + 32 + quad * 8]);
            #pragma unroll
            for (int dt = 0; dt < 4; ++dt) {
                oacc[1][dt] = __builtin_amdgcn_mfma_f32_16x16x32_bf16(aV[dt][0], bP0, oacc[1][dt], 0, 0, 0);
                oacc[1][dt] = __builtin_amdgcn_mfma_f32_16x16x32_bf16(aV[dt][1], bP1, oacc[1][dt], 0, 0, 0);
            }
            lacc[1] = __builtin_amdgcn_mfma_f32_16x16x32_bf16(ones, bP0, lacc[1], 0, 0, 0);
            lacc[1] = __builtin_amdgcn_mfma_f32_16x16x32_bf16(ones, bP1, lacc[1], 0, 0, 0);
        }
    }

    // normalize + store; l = lacc[h][0] (full column sum, identical all lanes/regs)
    const int bb = bh / H_NUM, hh = bh % H_NUM;
    #pragma unroll
    for (int h = 0; h < 2; ++h) {
        float inv = 1.f / lacc[h][0];
        int q = q0 + h * 64 + wv * 16 + lr;
        #pragma unroll
        for (int dt = 0; dt < 4; ++dt) {
            ushort4 u;
            u.x = f2b(oacc[h][dt][0] * inv);
            u.y = f2b(oacc[h][dt][1] * inv);
            u.z = f2b(oacc[h][dt][2] * inv);
            u.w = f2b(oacc[h][dt][3] * inv);
            *reinterpret_cast<ushort4*>(
                &Y[(size_t)(bb * T_SEQ + q) * C_DIM + hh * 64 + dt * 16 + quad * 4]) = u;
        }
    }
}

// ---------------------------------------------------------------------------
// Output projection: Y[8192,768](bf16) x wto[768,768]([n][k]) + bias -> fp32
// 128x64 tiles -> grid 768 blocks (3/CU).
// ---------------------------------------------------------------------------
__global__ __launch_bounds__(256) void out_gemm(
    const unsigned short* __restrict__ Y, const unsigned short* __restrict__ wt,
    const float* __restrict__ bias, float* __restrict__ out)
{
    __shared__ unsigned short As[128 * 64];
    __shared__ unsigned short Bs[64 * 64];
    const int tid  = threadIdx.x;
    const int m0   = blockIdx.x * 128;
    const int n0   = blockIdx.y * 64;
    const int lane = tid & 63;
    const int wv   = tid >> 6;
    const int wr   = wv >> 1, wc = wv & 1;   // wave tile: 64m x 32n
    const int quad = lane >> 4;
    const int lr   = lane & 15;
    const int srow = lane >> 3;
    const int dch  = (lane & 7) ^ srow;

    f32x4 acc[4][2] = {};

    for (int kk = 0; kk < C_DIM; kk += 64) {
        __syncthreads();
        #pragma unroll
        for (int i = 0; i < 4; ++i) {
            int inst = wv * 4 + i;
            int r = inst * 8 + srow;
            load_lds16(Y + (size_t)(m0 + r) * C_DIM + kk + dch * 8, As + inst * 512);
        }
        #pragma unroll
        for (int i = 0; i < 2; ++i) {
            int inst = wv * 2 + i;
            int r = inst * 8 + srow;
            load_lds16(wt + (size_t)(n0 + r) * C_DIM + kk + dch * 8, Bs + inst * 512);
        }
        __syncthreads();
        #pragma unroll
        for (int k2 = 0; k2 < 2; ++k2) {
            bf16x8 af[4], bf[2];
            #pragma unroll
            for (int mt = 0; mt < 4; ++mt)
                af[mt] = *reinterpret_cast<const bf16x8*>(
                    &As[(wr * 64 + mt * 16 + lr) * 64 + (((k2 * 4 + quad) ^ (lr & 7)) * 8)]);
            #pragma unroll
            for (int nt = 0; nt < 2; ++nt)
                bf[nt] = *reinterpret_cast<const bf16x8*>(
                    &Bs[(wc * 32 + nt * 16 + lr) * 64 + (((k2 * 4 + quad) ^ (lr & 7)) * 8)]);
            #pragma unroll
            for (int mt = 0; mt < 4; ++mt)
                #pragma unroll
                for (int nt = 0; nt < 2; ++nt)
                    acc[mt][nt] = __builtin_amdgcn_mfma_f32_16x16x32_bf16(af[mt], bf[nt], acc[mt][nt], 0, 0, 0);
        }
    }

    #pragma unroll
    for (int nt = 0; nt < 2; ++nt) {
        int j = n0 + wc * 32 + nt * 16 + lr;
        float bj = bias[j];
        #pragma unroll
        for (int mt = 0; mt < 4; ++mt)
            #pragma unroll
            for (int reg = 0; reg < 4; ++reg) {
                int i = m0 + wr * 64 + mt * 16 + quad * 4 + reg;
                out[(size_t)i * C_DIM + j] = acc[mt][nt][reg] + bj;
            }
    }
}

// ---------------------------------------------------------------------------
extern "C" void kernel_launch(void* const* d_in, const int* in_sizes, int n_in,
                              void* d_out, int out_size, void* d_ws, size_t ws_size,
                              hipStream_t stream) {
    const float* x     = (const float*)d_in[0];
    const float* qkv_w = (const float*)d_in[1];
    const float* qkv_b = (const float*)d_in[2];
    const float* out_w = (const float*)d_in[3];
    const float* out_b = (const float*)d_in[4];
    float* out = (float*)d_out;

    unsigned short* xb  = (unsigned short*)d_ws;            // [8192][768], reused as Y
    unsigned short* wtq = xb  + (size_t)8192 * 768;         // [2304][768]
    unsigned short* wto = wtq + (size_t)2304 * 768;         // [768][768]
    unsigned short* Qs  = wto + (size_t)768 * 768;
    unsigned short* Kg  = Qs  + (size_t)BHN * T_SEQ * D_HEAD;
    unsigned short* Vt  = Kg  + (size_t)BHN * T_SEQ * D_HEAD;
    unsigned short* Y   = xb;   // alias: xb dead after qkv_gemm

    prep      <<<6720, 256, 0, stream>>>(x, qkv_w, out_w, xb, wtq, wto);
    qkv_gemm  <<<dim3(64, 18), 256, 0, stream>>>(xb, wtq, qkv_b, Qs, Kg, Vt);
    flash_attn<<<dim3(32 * BHN), 256, 0, stream>>>(Qs, Kg, Vt, Y);
    out_gemm  <<<dim3(64, 12), 256, 0, stream>>>(Y, wto, out_b, out);
}

// Round 8
// 352.894 us; speedup vs baseline: 1.0833x; 1.0833x over previous
//
#include <hip/hip_runtime.h>
#include <hip/hip_bf16.h>

// Problem constants: B=2, T=4096, C=768, H=12, D=64
#define T_SEQ 4096
#define C_DIM 768
#define H_NUM 12
#define D_HEAD 64
#define N3    2304   // 3*C
#define BHN   24     // B*H

typedef __bf16 bf16x8 __attribute__((ext_vector_type(8)));
typedef float  f32x4  __attribute__((ext_vector_type(4)));

// fp32 -> bf16 (round-to-nearest-even), raw bits
__device__ inline unsigned short f2b(float f) {
    unsigned int x = __float_as_uint(f);
    unsigned int r = (x + 0x7FFFu + ((x >> 16) & 1u)) >> 16;
    return (unsigned short)r;
}

// pack two f32 -> two bf16 (TRUNCATED) in one v_perm_b32: low half = lo
__device__ inline unsigned int pack_trunc(float lo, float hi) {
    return __builtin_amdgcn_perm(__float_as_uint(hi), __float_as_uint(lo), 0x07060302u);
}

// 16B-per-lane async global->LDS (dest = wave-uniform base + lane*16)
__device__ inline void load_lds16(const unsigned short* g, unsigned short* l) {
    __builtin_amdgcn_global_load_lds(
        (const __attribute__((address_space(1))) unsigned int*)(g),
        (__attribute__((address_space(3))) unsigned int*)(l),
        16, 0, 0);
}

// ---------------------------------------------------------------------------
// prep: fused [convert x -> bf16] + [transpose qkv_w] + [transpose out_w]
// ---------------------------------------------------------------------------
__device__ inline void transpose_tile(const float* __restrict__ in,
                                      unsigned short* __restrict__ out,
                                      unsigned short* Ts, int k0, int n0,
                                      int R, int Cc, int tid)
{
    #pragma unroll
    for (int it = 0; it < 4; ++it) {
        int idx = tid + it * 256;
        int r = idx >> 4, c4 = idx & 15;
        float4 v = *reinterpret_cast<const float4*>(&in[(size_t)(k0 + r) * Cc + n0 + c4 * 4]);
        Ts[(c4 * 4 + 0) * 72 + r] = f2b(v.x);
        Ts[(c4 * 4 + 1) * 72 + r] = f2b(v.y);
        Ts[(c4 * 4 + 2) * 72 + r] = f2b(v.z);
        Ts[(c4 * 4 + 3) * 72 + r] = f2b(v.w);
    }
    __syncthreads();
    #pragma unroll
    for (int it = 0; it < 2; ++it) {
        int idx = tid + it * 256;
        int row = idx >> 3, ch = idx & 7;
        *reinterpret_cast<uint4*>(&out[(size_t)(n0 + row) * R + k0 + ch * 8]) =
            *reinterpret_cast<const uint4*>(&Ts[row * 72 + ch * 8]);
    }
}

__global__ __launch_bounds__(256) void prep(
    const float* __restrict__ x, const float* __restrict__ qkv_w,
    const float* __restrict__ out_w,
    unsigned short* __restrict__ xb, unsigned short* __restrict__ wtq,
    unsigned short* __restrict__ wto)
{
    __shared__ unsigned short Ts[64 * 72];
    const int b = blockIdx.x, tid = threadIdx.x;
    if (b < 6144) {
        int idx = b * 256 + tid;
        float4 v = reinterpret_cast<const float4*>(x)[idx];
        ushort4 u;
        u.x = f2b(v.x); u.y = f2b(v.y); u.z = f2b(v.z); u.w = f2b(v.w);
        reinterpret_cast<ushort4*>(xb)[idx] = u;
    } else if (b < 6576) {
        int bb = b - 6144;
        transpose_tile(qkv_w, wtq, Ts, (bb % 12) * 64, (bb / 12) * 64, C_DIM, N3, tid);
    } else {
        int bb = b - 6576;
        transpose_tile(out_w, wto, Ts, (bb % 12) * 64, (bb / 12) * 64, C_DIM, C_DIM, tid);
    }
}

// ---------------------------------------------------------------------------
// QKV projection: xb[8192,768] x wtq[2304,768]([n][k]) + bias, all bf16 MFMA.
// 128x128 tile, BK=64. Q scaled by 0.125*log2e. V written via LDS transpose
// (coalesced 16B stores) as [B,H,D,T].
// ---------------------------------------------------------------------------
__global__ __launch_bounds__(256) void qkv_gemm(
    const unsigned short* __restrict__ xb, const unsigned short* __restrict__ wt,
    const float* __restrict__ bias,
    unsigned short* __restrict__ Q, unsigned short* __restrict__ K,
    unsigned short* __restrict__ Vt)
{
    __shared__ unsigned short SH[128 * 128];   // As | Bs ; reused as Ct in V epilogue
    unsigned short* As = SH;                   // [128][64] xor-swizzled chunks
    unsigned short* Bs = SH + 128 * 64;        // [128][64]
    const int tid  = threadIdx.x;
    const int m0   = blockIdx.x * 128;
    const int n0   = blockIdx.y * 128;
    const int lane = tid & 63;
    const int wv   = tid >> 6;
    const int wr   = wv >> 1, wc = wv & 1;
    const int quad = lane >> 4;
    const int lr   = lane & 15;
    const int srow = lane >> 3;
    const int dch  = (lane & 7) ^ srow;

    f32x4 acc[4][4] = {};

    for (int kk = 0; kk < C_DIM; kk += 64) {
        __syncthreads();
        #pragma unroll
        for (int i = 0; i < 4; ++i) {
            int inst = wv * 4 + i;
            int r = inst * 8 + srow;
            load_lds16(xb + (size_t)(m0 + r) * C_DIM + kk + dch * 8, As + inst * 512);
            load_lds16(wt + (size_t)(n0 + r) * C_DIM + kk + dch * 8, Bs + inst * 512);
        }
        __syncthreads();
        #pragma unroll
        for (int k2 = 0; k2 < 2; ++k2) {
            bf16x8 af[4], bf[4];
            #pragma unroll
            for (int mt = 0; mt < 4; ++mt)
                af[mt] = *reinterpret_cast<const bf16x8*>(
                    &As[(wr * 64 + mt * 16 + lr) * 64 + (((k2 * 4 + quad) ^ (lr & 7)) * 8)]);
            #pragma unroll
            for (int nt = 0; nt < 4; ++nt)
                bf[nt] = *reinterpret_cast<const bf16x8*>(
                    &Bs[(wc * 64 + nt * 16 + lr) * 64 + (((k2 * 4 + quad) ^ (lr & 7)) * 8)]);
            #pragma unroll
            for (int mt = 0; mt < 4; ++mt)
                #pragma unroll
                for (int nt = 0; nt < 4; ++nt)
                    acc[mt][nt] = __builtin_amdgcn_mfma_f32_16x16x32_bf16(af[mt], bf[nt], acc[mt][nt], 0, 0, 0);
        }
    }

    const int whichblk = n0 / C_DIM;   // 0=Q,1=K,2=V (uniform; 768 % 128 == 0)
    if (whichblk == 2) {
        // --- V epilogue: transpose through LDS, coalesced 16B stores ---
        __syncthreads();
        #pragma unroll
        for (int nt = 0; nt < 4; ++nt) {
            int dp = wc * 64 + nt * 16 + lr;          // n within tile = 0..127
            float bj = bias[n0 + dp];
            #pragma unroll
            for (int mt = 0; mt < 4; ++mt) {
                int t0 = wr * 64 + mt * 16 + quad * 4;  // 4 consecutive t
                ushort4 u;
                u.x = f2b(acc[mt][nt][0] + bj);
                u.y = f2b(acc[mt][nt][1] + bj);
                u.z = f2b(acc[mt][nt][2] + bj);
                u.w = f2b(acc[mt][nt][3] + bj);
                int cs = (t0 >> 2) ^ ((dp & 15) << 1);   // even-XOR: keeps 16B pairs
                *reinterpret_cast<ushort4*>(&SH[dp * 128 + cs * 4]) = u;
            }
        }
        __syncthreads();
        const int bb = m0 >> 12;
        const int t_base = m0 & 4095;
        const int h_base = (n0 - 2 * C_DIM) >> 6;
        #pragma unroll
        for (int i = 0; i < 8; ++i) {
            int idx = i * 256 + tid;
            int row = idx >> 4, cc = idx & 15;
            int pc = ((2 * cc) ^ ((row & 15) << 1)) * 4;
            uint4 val = *reinterpret_cast<const uint4*>(&SH[row * 128 + pc]);
            int head = h_base + (row >> 6);
            int d = row & 63;
            *reinterpret_cast<uint4*>(
                &Vt[((size_t)(bb * H_NUM + head) * D_HEAD + d) * T_SEQ + t_base + cc * 8]) = val;
        }
    } else {
        // --- Q/K epilogue: direct stores (16-lane 32B segments) ---
        const int head0 = ((n0 % C_DIM) + wc * 64) >> 6;
        #pragma unroll
        for (int nt = 0; nt < 4; ++nt) {
            int d = nt * 16 + lr;
            float bj = bias[n0 + wc * 64 + nt * 16 + lr];
            #pragma unroll
            for (int mt = 0; mt < 4; ++mt) {
                #pragma unroll
                for (int reg = 0; reg < 4; ++reg) {
                    int i = m0 + wr * 64 + mt * 16 + quad * 4 + reg;
                    int bb = i >> 12, t = i & 4095;
                    float val = acc[mt][nt][reg] + bj;
                    size_t base = (size_t)(bb * H_NUM + head0) * T_SEQ + t;
                    if (whichblk == 0)
                        Q[base * D_HEAD + d] = f2b(val * 0.18033688011f);  // 0.125*log2(e)
                    else
                        K[base * D_HEAD + d] = f2b(val);
                }
            }
        }
    }
}

// ---------------------------------------------------------------------------
// Flash attention (causal), R8: barrier-free + register-pipelined.
// One block = 128 queries of one (b,h); 4 waves x (16 q x 2 halves).
// K-fragments are explicitly double-buffered in REGISTERS: tile kt+1's aK is
// loaded before computing tile kt (one full compute body ~700 cyc of lead, vs
// R7 where loads drained cold at ~200-500 cyc each). V-fragments issued at
// the top of each step (lead = S-MFMA + exp + pack ~500 cyc > L2 latency).
// No K/V LDS, no __syncthreads. LDS = P strips only. XCD-swizzled mapping
// keeps each bh's 1 MB K+V in its XCD L2; all 4 waves read identical K/V
// lines (L1 serves the redundancy). Max-free log2 softmax; l via ones-MFMA.
// ---------------------------------------------------------------------------
struct KFrags { bf16x8 k[4][2]; };

__device__ inline void load_k(const unsigned short* __restrict__ Kb, int kt,
                              int lr, int quad, KFrags& f)
{
    const unsigned short* Kt = Kb + (size_t)kt * 64 * D_HEAD;
    #pragma unroll
    for (int mt = 0; mt < 4; ++mt)
        #pragma unroll
        for (int k2 = 0; k2 < 2; ++k2)
            f.k[mt][k2] = *reinterpret_cast<const bf16x8*>(
                &Kt[(mt * 16 + lr) * D_HEAD + k2 * 32 + quad * 8]);
}

__device__ inline void attn_step(
    int kt, int diag0, int last, int q0, int wv, int lr, int quad,
    const unsigned short* __restrict__ Vb,
    const KFrags& f, const bf16x8 (&bQ)[2][2], const bf16x8& ones,
    unsigned short* Pw0, unsigned short* Pw1,
    f32x4 (&oacc)[2][4], f32x4 (&lacc)[2])
{
    const f32x4 zf = {};
    const bool doh0 = (kt <= diag0);

    // V A-frags issued EARLY (consumed after S+exp+pack ~500 cyc later)
    bf16x8 aV[4][2];
    #pragma unroll
    for (int mt = 0; mt < 4; ++mt)
        #pragma unroll
        for (int k2 = 0; k2 < 2; ++k2)
            aV[mt][k2] = *reinterpret_cast<const bf16x8*>(
                &Vb[(size_t)(mt * 16 + lr) * T_SEQ + kt * 64 + k2 * 32 + quad * 8]);

    // S^T[key][q] for both halves
    f32x4 st0[4], st1[4];
    #pragma unroll
    for (int mt = 0; mt < 4; ++mt) {
        st1[mt] = __builtin_amdgcn_mfma_f32_16x16x32_bf16(f.k[mt][0], bQ[1][0], zf, 0, 0, 0);
        st1[mt] = __builtin_amdgcn_mfma_f32_16x16x32_bf16(f.k[mt][1], bQ[1][1], st1[mt], 0, 0, 0);
    }
    if (doh0) {
        #pragma unroll
        for (int mt = 0; mt < 4; ++mt) {
            st0[mt] = __builtin_amdgcn_mfma_f32_16x16x32_bf16(f.k[mt][0], bQ[0][0], zf, 0, 0, 0);
            st0[mt] = __builtin_amdgcn_mfma_f32_16x16x32_bf16(f.k[mt][1], bQ[0][1], st0[mt], 0, 0, 0);
        }
    }

    // causal masks (diagonal tiles only)
    if (kt == diag0) {
        int qg = q0 + wv * 16 + lr;
        #pragma unroll
        for (int mt = 0; mt < 4; ++mt)
            #pragma unroll
            for (int reg = 0; reg < 4; ++reg)
                if (kt * 64 + mt * 16 + quad * 4 + reg > qg) st0[mt][reg] = -INFINITY;
    }
    if (kt == last) {
        int qg = q0 + 64 + wv * 16 + lr;
        #pragma unroll
        for (int mt = 0; mt < 4; ++mt)
            #pragma unroll
            for (int reg = 0; reg < 4; ++reg)
                if (kt * 64 + mt * 16 + quad * 4 + reg > qg) st1[mt][reg] = -INFINITY;
    }

    // p = exp2(s); pack truncated; write per-half strips (same-wave consume)
    #pragma unroll
    for (int mt = 0; mt < 4; ++mt) {
        #pragma unroll
        for (int reg = 0; reg < 4; ++reg)
            st1[mt][reg] = __builtin_amdgcn_exp2f(st1[mt][reg]);
        uint2 u;
        u.x = pack_trunc(st1[mt][0], st1[mt][1]);
        u.y = pack_trunc(st1[mt][2], st1[mt][3]);
        *reinterpret_cast<uint2*>(&Pw1[lr * 72 + mt * 16 + quad * 4]) = u;
    }
    if (doh0) {
        #pragma unroll
        for (int mt = 0; mt < 4; ++mt) {
            #pragma unroll
            for (int reg = 0; reg < 4; ++reg)
                st0[mt][reg] = __builtin_amdgcn_exp2f(st0[mt][reg]);
            uint2 u;
            u.x = pack_trunc(st0[mt][0], st0[mt][1]);
            u.y = pack_trunc(st0[mt][2], st0[mt][3]);
            *reinterpret_cast<uint2*>(&Pw0[lr * 72 + mt * 16 + quad * 4]) = u;
        }
    }

    // O^T += V^T P^T ; l += 1^T P
    if (doh0) {
        bf16x8 bP0 = *reinterpret_cast<const bf16x8*>(&Pw0[lr * 72 + quad * 8]);
        bf16x8 bP1 = *reinterpret_cast<const bf16x8*>(&Pw0[lr * 72 + 32 + quad * 8]);
        #pragma unroll
        for (int dt = 0; dt < 4; ++dt) {
            oacc[0][dt] = __builtin_amdgcn_mfma_f32_16x16x32_bf16(aV[dt][0], bP0, oacc[0][dt], 0, 0, 0);
            oacc[0][dt] = __builtin_amdgcn_mfma_f32_16x16x32_bf16(aV[dt][1], bP1, oacc[0][dt], 0, 0, 0);
        }
        lacc[0] = __builtin_amdgcn_mfma_f32_16x16x32_bf16(ones, bP0, lacc[0], 0, 0, 0);
        lacc[0] = __builtin_amdgcn_mfma_f32_16x16x32_bf16(ones, bP1, lacc[0], 0, 0, 0);
    }
    {
        bf16x8 bP0 = *reinterpret_cast<const bf16x8*>(&Pw1[lr * 72 + quad * 8]);
        bf16x8 bP1 = *reinterpret_cast<const bf16x8*>(&Pw1[lr * 72 + 32 + quad * 8]);
        #pragma unroll
        for (int dt = 0; dt < 4; ++dt) {
            oacc[1][dt] = __builtin_amdgcn_mfma_f32_16x16x32_bf16(aV[dt][0], bP0, oacc[1][dt], 0, 0, 0);
            oacc[1][dt] = __builtin_amdgcn_mfma_f32_16x16x32_bf16(aV[dt][1], bP1, oacc[1][dt], 0, 0, 0);
        }
        lacc[1] = __builtin_amdgcn_mfma_f32_16x16x32_bf16(ones, bP0, lacc[1], 0, 0, 0);
        lacc[1] = __builtin_amdgcn_mfma_f32_16x16x32_bf16(ones, bP1, lacc[1], 0, 0, 0);
    }
}

__global__ __launch_bounds__(256, 2) void flash_attn(
    const unsigned short* __restrict__ Q, const unsigned short* __restrict__ K,
    const unsigned short* __restrict__ Vt, unsigned short* __restrict__ Y)
{
    __shared__ unsigned short Ps[2][64 * 72];   // [half][q][key] per-wave strips
    const int tid  = threadIdx.x;
    const int lane = tid & 63;
    const int wv   = tid >> 6;
    const int quad = lane >> 4;
    const int lr   = lane & 15;

    // XCD-aware mapping: bid%8 = XCD (HW round-robin); each XCD owns 3 bh.
    const int bid = blockIdx.x;
    const int xcd = bid & 7;
    const int jj  = (bid >> 3) % 3;
    const int bh  = xcd * 3 + jj;
    const int qt  = 31 - (bid / 24);      // heavy q-tiles first
    const int q0  = qt * 128;
    const int diag0 = 2 * qt;             // kt index of half-0 diagonal
    const int last  = diag0 + 1;          // kt index of half-1 diagonal

    const unsigned short* Qb = Q  + (size_t)bh * T_SEQ * D_HEAD;
    const unsigned short* Kb = K  + (size_t)bh * T_SEQ * D_HEAD;
    const unsigned short* Vb = Vt + (size_t)bh * D_HEAD * T_SEQ;

    bf16x8 bQ[2][2];
    #pragma unroll
    for (int h = 0; h < 2; ++h)
        #pragma unroll
        for (int k2 = 0; k2 < 2; ++k2)
            bQ[h][k2] = *reinterpret_cast<const bf16x8*>(
                &Qb[(size_t)(q0 + h * 64 + wv * 16 + lr) * D_HEAD + k2 * 32 + quad * 8]);

    bf16x8 ones;
    #pragma unroll
    for (int i = 0; i < 8; ++i) ones[i] = (__bf16)1.0f;

    f32x4 oacc[2][4] = {};
    f32x4 lacc[2] = {};

    unsigned short* Pw0 = &Ps[0][(wv * 16) * 72];
    unsigned short* Pw1 = &Ps[1][(wv * 16) * 72];

    // two-stage register pipeline over kt (parity-unrolled: no dynamic
    // indexing of the frag sets -> they stay in VGPRs)
    KFrags fA, fB;
    load_k(Kb, 0, lr, quad, fA);
    for (int kt = 0; kt <= last; kt += 2) {
        int kn1 = (kt + 1 <= last) ? kt + 1 : last;   // clamp: redundant, in-bounds
        load_k(Kb, kn1, lr, quad, fB);
        attn_step(kt, diag0, last, q0, wv, lr, quad, Vb, fA, bQ, ones, Pw0, Pw1, oacc, lacc);
        if (kt + 1 <= last) {
            int kn2 = (kt + 2 <= last) ? kt + 2 : last;
            load_k(Kb, kn2, lr, quad, fA);
            attn_step(kt + 1, diag0, last, q0, wv, lr, quad, Vb, fB, bQ, ones, Pw0, Pw1, oacc, lacc);
        }
    }

    // normalize + store; l = lacc[h][0] (full column sum, identical all lanes)
    const int bb = bh / H_NUM, hh = bh % H_NUM;
    #pragma unroll
    for (int h = 0; h < 2; ++h) {
        float inv = 1.f / lacc[h][0];
        int q = q0 + h * 64 + wv * 16 + lr;
        #pragma unroll
        for (int dt = 0; dt < 4; ++dt) {
            ushort4 u;
            u.x = f2b(oacc[h][dt][0] * inv);
            u.y = f2b(oacc[h][dt][1] * inv);
            u.z = f2b(oacc[h][dt][2] * inv);
            u.w = f2b(oacc[h][dt][3] * inv);
            *reinterpret_cast<ushort4*>(
                &Y[(size_t)(bb * T_SEQ + q) * C_DIM + hh * 64 + dt * 16 + quad * 4]) = u;
        }
    }
}

// ---------------------------------------------------------------------------
// Output projection: Y[8192,768](bf16) x wto[768,768]([n][k]) + bias -> fp32
// 128x64 tiles -> grid 768 blocks (3/CU).
// ---------------------------------------------------------------------------
__global__ __launch_bounds__(256) void out_gemm(
    const unsigned short* __restrict__ Y, const unsigned short* __restrict__ wt,
    const float* __restrict__ bias, float* __restrict__ out)
{
    __shared__ unsigned short As[128 * 64];
    __shared__ unsigned short Bs[64 * 64];
    const int tid  = threadIdx.x;
    const int m0   = blockIdx.x * 128;
    const int n0   = blockIdx.y * 64;
    const int lane = tid & 63;
    const int wv   = tid >> 6;
    const int wr   = wv >> 1, wc = wv & 1;   // wave tile: 64m x 32n
    const int quad = lane >> 4;
    const int lr   = lane & 15;
    const int srow = lane >> 3;
    const int dch  = (lane & 7) ^ srow;

    f32x4 acc[4][2] = {};

    for (int kk = 0; kk < C_DIM; kk += 64) {
        __syncthreads();
        #pragma unroll
        for (int i = 0; i < 4; ++i) {
            int inst = wv * 4 + i;
            int r = inst * 8 + srow;
            load_lds16(Y + (size_t)(m0 + r) * C_DIM + kk + dch * 8, As + inst * 512);
        }
        #pragma unroll
        for (int i = 0; i < 2; ++i) {
            int inst = wv * 2 + i;
            int r = inst * 8 + srow;
            load_lds16(wt + (size_t)(n0 + r) * C_DIM + kk + dch * 8, Bs + inst * 512);
        }
        __syncthreads();
        #pragma unroll
        for (int k2 = 0; k2 < 2; ++k2) {
            bf16x8 af[4], bf[2];
            #pragma unroll
            for (int mt = 0; mt < 4; ++mt)
                af[mt] = *reinterpret_cast<const bf16x8*>(
                    &As[(wr * 64 + mt * 16 + lr) * 64 + (((k2 * 4 + quad) ^ (lr & 7)) * 8)]);
            #pragma unroll
            for (int nt = 0; nt < 2; ++nt)
                bf[nt] = *reinterpret_cast<const bf16x8*>(
                    &Bs[(wc * 32 + nt * 16 + lr) * 64 + (((k2 * 4 + quad) ^ (lr & 7)) * 8)]);
            #pragma unroll
            for (int mt = 0; mt < 4; ++mt)
                #pragma unroll
                for (int nt = 0; nt < 2; ++nt)
                    acc[mt][nt] = __builtin_amdgcn_mfma_f32_16x16x32_bf16(af[mt], bf[nt], acc[mt][nt], 0, 0, 0);
        }
    }

    #pragma unroll
    for (int nt = 0; nt < 2; ++nt) {
        int j = n0 + wc * 32 + nt * 16 + lr;
        float bj = bias[j];
        #pragma unroll
        for (int mt = 0; mt < 4; ++mt)
            #pragma unroll
            for (int reg = 0; reg < 4; ++reg) {
                int i = m0 + wr * 64 + mt * 16 + quad * 4 + reg;
                out[(size_t)i * C_DIM + j] = acc[mt][nt][reg] + bj;
            }
    }
}

// ---------------------------------------------------------------------------
extern "C" void kernel_launch(void* const* d_in, const int* in_sizes, int n_in,
                              void* d_out, int out_size, void* d_ws, size_t ws_size,
                              hipStream_t stream) {
    const float* x     = (const float*)d_in[0];
    const float* qkv_w = (const float*)d_in[1];
    const float* qkv_b = (const float*)d_in[2];
    const float* out_w = (const float*)d_in[3];
    const float* out_b = (const float*)d_in[4];
    float* out = (float*)d_out;

    unsigned short* xb  = (unsigned short*)d_ws;            // [8192][768], reused as Y
    unsigned short* wtq = xb  + (size_t)8192 * 768;         // [2304][768]
    unsigned short* wto = wtq + (size_t)2304 * 768;         // [768][768]
    unsigned short* Qs  = wto + (size_t)768 * 768;
    unsigned short* Kg  = Qs  + (size_t)BHN * T_SEQ * D_HEAD;
    unsigned short* Vt  = Kg  + (size_t)BHN * T_SEQ * D_HEAD;
    unsigned short* Y   = xb;   // alias: xb dead after qkv_gemm

    prep      <<<6720, 256, 0, stream>>>(x, qkv_w, out_w, xb, wtq, wto);
    qkv_gemm  <<<dim3(64, 18), 256, 0, stream>>>(xb, wtq, qkv_b, Qs, Kg, Vt);
    flash_attn<<<dim3(32 * BHN), 256, 0, stream>>>(Qs, Kg, Vt, Y);
    out_gemm  <<<dim3(64, 12), 256, 0, stream>>>(Y, wto, out_b, out);
}